// Round 3
// baseline (978.058 us; speedup 1.0000x reference)
//
#include <hip/hip_runtime.h>
#include <hip/hip_bf16.h>
#include <stdint.h>

// ---------- types / helpers ----------
typedef unsigned short u16;
using bf16x8 = __attribute__((ext_vector_type(8))) short;  // 8 bf16 in 4 VGPRs
using f32x4  = __attribute__((ext_vector_type(4))) float;  // MFMA accumulator
typedef unsigned short u16x4 __attribute__((ext_vector_type(4)));

#define AS1 __attribute__((address_space(1)))
#define AS3 __attribute__((address_space(3)))

__device__ __forceinline__ float bf2f(u16 x) {
    union { unsigned int u; float f; } v; v.u = ((unsigned int)x) << 16; return v.f;
}
__device__ __forceinline__ u16 f2bf(float f) {
    union { float f; unsigned int u; } v; v.f = f;
    return (u16)((v.u + 0x7fffu + ((v.u >> 16) & 1u)) >> 16);  // RNE
}

#define ACT_NONE 0
#define ACT_SOFTPLUS 1

// ---------- generic bf16 GEMM: C[M,N] = A[M,K] * B[N,K]^T ----------
// 128x128 tile, BK=64, 256 threads (4 waves 2x2), 16x16x32 bf16 MFMA.
__global__ __launch_bounds__(256) void gemm_bt_kernel(
    const u16* __restrict__ A, int lda,
    const u16* __restrict__ B,              // ldb == K
    float* __restrict__ Cf, u16* __restrict__ Cb,
    const float* __restrict__ bias,
    int ldc, int M, int N, int K, int Nreal,
    int flipA, int flipC, int act)
{
    __shared__ __align__(16) u16 As[128 * 64];
    __shared__ __align__(16) u16 Bs[128 * 64];

    const int tid  = threadIdx.x;
    const int bm   = blockIdx.y * 128;
    const int bn   = blockIdx.x * 128;
    const int lane = tid & 63;
    const int wid  = tid >> 6;
    const int wr   = (wid >> 1) * 64;
    const int wc   = (wid & 1) * 64;
    const int l15  = lane & 15;
    const int l4   = lane >> 4;

    f32x4 acc[4][4];
    const f32x4 vzero = {0.f, 0.f, 0.f, 0.f};
    #pragma unroll
    for (int i = 0; i < 4; ++i)
        #pragma unroll
        for (int j = 0; j < 4; ++j) acc[i][j] = vzero;

    const int nK = K >> 6;
    for (int k0 = 0; k0 < nK; ++k0) {
        #pragma unroll
        for (int i = 0; i < 4; ++i) {
            int off  = i * 4096 + tid * 16;     // byte offset in tile
            int row  = off >> 7;
            int colB = off & 127;
            int rowG = bm + row;
            if (flipA) { int b = rowG >> 11; int l = rowG & 2047; rowG = (b << 11) + (2047 - l); }
            const char* src = (const char*)A + ((size_t)rowG * lda + ((size_t)k0 << 6)) * 2 + colB;
            __builtin_amdgcn_global_load_lds((const AS1 unsigned int*)src,
                                             (AS3 unsigned int*)((char*)As + off), 16, 0, 0);
        }
        #pragma unroll
        for (int i = 0; i < 4; ++i) {
            int off  = i * 4096 + tid * 16;
            int row  = off >> 7;
            int colB = off & 127;
            int rowG = bn + row;
            const char* src = (const char*)B + ((size_t)rowG * K + ((size_t)k0 << 6)) * 2 + colB;
            __builtin_amdgcn_global_load_lds((const AS1 unsigned int*)src,
                                             (AS3 unsigned int*)((char*)Bs + off), 16, 0, 0);
        }
        __syncthreads();

        #pragma unroll
        for (int kk = 0; kk < 2; ++kk) {
            bf16x8 af[4], bfr[4];
            #pragma unroll
            for (int mt = 0; mt < 4; ++mt) {
                int row = wr + mt * 16 + l15;
                af[mt] = *(const bf16x8*)((const char*)As + row * 128 + kk * 64 + l4 * 16);
            }
            #pragma unroll
            for (int nt = 0; nt < 4; ++nt) {
                int row = wc + nt * 16 + l15;
                bfr[nt] = *(const bf16x8*)((const char*)Bs + row * 128 + kk * 64 + l4 * 16);
            }
            #pragma unroll
            for (int mt = 0; mt < 4; ++mt)
                #pragma unroll
                for (int nt = 0; nt < 4; ++nt)
                    acc[mt][nt] = __builtin_amdgcn_mfma_f32_16x16x32_bf16(
                        af[mt], bfr[nt], acc[mt][nt], 0, 0, 0);
        }
        __syncthreads();
    }

    #pragma unroll
    for (int mt = 0; mt < 4; ++mt) {
        #pragma unroll
        for (int nt = 0; nt < 4; ++nt) {
            int col = bn + wc + nt * 16 + l15;
            if (col >= Nreal) continue;
            #pragma unroll
            for (int r = 0; r < 4; ++r) {
                int rowG = bm + wr + mt * 16 + l4 * 4 + r;
                float v = acc[mt][nt][r];
                if (act == ACT_SOFTPLUS) {
                    v += bias[col];
                    v = fmaxf(v, 0.f) + log1pf(__expf(-fabsf(v)));
                }
                int rw = rowG;
                if (flipC) { int b = rw >> 11; int l = rw & 2047; rw = (b << 11) + (2047 - l); }
                if (Cb) Cb[(size_t)rw * ldc + col] = f2bf(v);
                else    Cf[(size_t)rw * ldc + col] = v;
            }
        }
    }
}

// ---------- causal depthwise conv (w=4) + silu, sliding-window ----------
// thread: one channel d, 16 consecutive rows. grid (8, 256).
__global__ void conv_silu_kernel(const u16* __restrict__ xz,   // [4096][4096], xi = cols 0..2047
                                 const float* __restrict__ cw, // [2048][4]
                                 const float* __restrict__ cb,
                                 u16* __restrict__ u)           // [4096][2048]
{
    int d  = blockIdx.x * 256 + threadIdx.x;   // 0..2047
    int r0 = blockIdx.y * 16;                  // 16 | 2048, blocks never straddle batches
    float w0 = cw[d*4+0], w1 = cw[d*4+1], w2 = cw[d*4+2], w3 = cw[d*4+3];
    float bias = cb[d];
    float x1, x2, x3;
    if (r0 & 2047) {   // not at batch start: halo rows exist
        x1 = bf2f(xz[(size_t)(r0-1) * 4096 + d]);
        x2 = bf2f(xz[(size_t)(r0-2) * 4096 + d]);
        x3 = bf2f(xz[(size_t)(r0-3) * 4096 + d]);
    } else { x1 = x2 = x3 = 0.f; }
    #pragma unroll
    for (int i = 0; i < 16; ++i) {
        int r = r0 + i;
        float x0 = bf2f(xz[(size_t)r * 4096 + d]);
        float acc = fmaf(w3, x0, fmaf(w2, x1, fmaf(w1, x2, fmaf(w0, x3, bias))));
        float sig = 1.f / (1.f + __expf(-acc));
        u[(size_t)r * 2048 + d] = f2bf(acc * sig);
        x3 = x2; x2 = x1; x1 = x0;
    }
}

// ---------- chunked selective scan ----------
// h_t = dA_t h_{t-1} + dBu_t composes affinely: over a chunk, h_out = P*h_in + S.
// part1: per-chunk (P,S) from h=0.  part2: serial chunk-prefix (32 steps).
// part3: re-scan each chunk from its h_in, emit y with fused gate epilogue.
// Layout P/S: [b][c][d][n] -> ((b*32+c)<<15) + d*16 + n.

#define NCH 32   // chunks per sequence
#define CSZ 64   // steps per chunk

__global__ __launch_bounds__(256) void scan_part1(
    const u16* __restrict__ delta, const u16* __restrict__ u,
    const float* __restrict__ dbc, const float* __restrict__ A_log,
    float* __restrict__ P, float* __restrict__ S)
{
    __shared__ __align__(16) u16   delta_s[CSZ * 16];
    __shared__ __align__(16) u16   u_s[CSZ * 16];
    __shared__ __align__(16) float b_s[CSZ * 16];

    const int tid = threadIdx.x;
    const int d0  = blockIdx.x * 16;
    const int c   = blockIdx.y;
    const int b   = blockIdx.z;
    const int dl  = tid >> 4;
    const int n   = tid & 15;
    const int d   = d0 + dl;
    const int s_  = tid >> 2;          // staging row (0..63)
    const int q4  = (tid & 3) * 4;

    {
        size_t row = (size_t)b * 2048 + c * CSZ + s_;
        *(u16x4*)&delta_s[s_ * 16 + q4] = *(const u16x4*)&delta[row * 2048 + d0 + q4];
        *(u16x4*)&u_s[s_ * 16 + q4]     = *(const u16x4*)&u[row * 2048 + d0 + q4];
        *(float4*)&b_s[s_ * 16 + q4]    = *(const float4*)&dbc[row * 96 + 64 + q4];
    }
    const float a2 = -__expf(A_log[d * 16 + n]) * 1.4426950408889634f;
    __syncthreads();

    float h = 0.f, p = 1.f;
    #pragma unroll 4
    for (int s = 0; s < CSZ; ++s) {
        float dv = bf2f(delta_s[s * 16 + dl]);
        float uv = bf2f(u_s[s * 16 + dl]);
        float Bn = b_s[s * 16 + n];
        float dA = exp2f(dv * a2);
        h = fmaf(dA, h, dv * uv * Bn);
        p *= dA;
    }
    size_t idx = (((size_t)(b * NCH + c)) << 15) + tid + (size_t)(d0 >> 4) * 4096;
    // idx = ((b*NCH+c)<<15) + d*16 + n;  d*16+n = d0*16 + dl*16 + n = d0*16 + tid
    P[idx] = p;
    S[idx] = h;
}

__global__ void scan_part2(const float* __restrict__ P, float* __restrict__ S)
{
    int i  = blockIdx.x * 256 + threadIdx.x;   // 0..65535 = b*32768 + d*16+n
    int b  = i >> 15;
    int dn = i & 32767;
    size_t base = ((size_t)b * NCH) << 15;
    float h = 0.f;
    #pragma unroll 4
    for (int c = 0; c < NCH; ++c) {
        size_t idx = base + ((size_t)c << 15) + dn;
        float p = P[idx];
        float s = S[idx];
        S[idx] = h;                 // overwrite with h_in for chunk c
        h = fmaf(p, h, s);
    }
}

__global__ __launch_bounds__(256) void scan_part3(
    const u16* __restrict__ delta, const u16* __restrict__ u,
    const float* __restrict__ dbc, const u16* __restrict__ xz,
    const float* __restrict__ A_log, const float* __restrict__ Dp,
    const float* __restrict__ Hin, u16* __restrict__ y)
{
    __shared__ __align__(16) u16   delta_s[CSZ * 16];
    __shared__ __align__(16) u16   u_s[CSZ * 16];
    __shared__ __align__(16) float bc_s[CSZ * 32];  // [s][0..15]=B, [16..31]=C
    __shared__ __align__(16) u16   z_s[CSZ * 16];

    const int tid = threadIdx.x;
    const int d0  = blockIdx.x * 16;
    const int c   = blockIdx.y;
    const int b   = blockIdx.z;
    const int dl  = tid >> 4;
    const int n   = tid & 15;
    const int d   = d0 + dl;
    const int s_  = tid >> 2;
    const int q4  = (tid & 3) * 4;
    const int g8  = (tid & 3) * 8;
    const size_t rbase = (size_t)b * 2048 + c * CSZ;

    {
        size_t row = rbase + s_;
        *(u16x4*)&delta_s[s_ * 16 + q4]   = *(const u16x4*)&delta[row * 2048 + d0 + q4];
        *(u16x4*)&u_s[s_ * 16 + q4]       = *(const u16x4*)&u[row * 2048 + d0 + q4];
        *(float4*)&bc_s[s_ * 32 + g8]     = *(const float4*)&dbc[row * 96 + 64 + g8];
        *(float4*)&bc_s[s_ * 32 + g8 + 4] = *(const float4*)&dbc[row * 96 + 64 + g8 + 4];
        *(u16x4*)&z_s[s_ * 16 + q4]       = *(const u16x4*)&xz[row * 4096 + 2048 + d0 + q4];
    }
    const float a2 = -__expf(A_log[d * 16 + n]) * 1.4426950408889634f;
    const float Dd = Dp[d];
    float h = Hin[(((size_t)(b * NCH + blockIdx.y)) << 15) + (size_t)d0 * 16 + tid];
    __syncthreads();

    for (int s = 0; s < CSZ; ++s) {
        float dv = bf2f(delta_s[s * 16 + dl]);
        float uv = bf2f(u_s[s * 16 + dl]);
        float Bn = bc_s[s * 32 + n];
        float Cn = bc_s[s * 32 + 16 + n];
        float dA = exp2f(dv * a2);
        h = fmaf(dA, h, dv * uv * Bn);
        float yp = h * Cn;
        yp += __shfl_xor(yp, 1);
        yp += __shfl_xor(yp, 2);
        yp += __shfl_xor(yp, 4);
        yp += __shfl_xor(yp, 8);
        if (n == 0) {
            float zv  = bf2f(z_s[s * 16 + dl]);
            float sig = 1.f / (1.f + __expf(-zv));
            float yv  = (yp + uv * Dd) * (zv * sig);
            y[(rbase + s) * 2048 + d] = f2bf(yv);
        }
    }
}

// ---------- elementwise ----------
__global__ void blend_kernel(const float* __restrict__ hidden, const float* __restrict__ mask,
                             const float* __restrict__ mw, const float* __restrict__ mb,
                             u16* __restrict__ xm)
{
    size_t i = (size_t)blockIdx.x * 256 + threadIdx.x;
    int r = (int)(i >> 10), c = (int)(i & 1023);
    float m = mask[r];
    float v = hidden[i] * m + (m * mw[c] + mb[c]) * (1.f - m);
    xm[i] = f2bf(v);
}

__global__ void final_kernel(const float* __restrict__ hidden, const float* __restrict__ mask,
                             const float* __restrict__ fo, const float* __restrict__ bo,
                             float* __restrict__ out)
{
    size_t i = (size_t)blockIdx.x * 256 + threadIdx.x;
    int r = (int)(i >> 10);
    float m = mask[r];
    out[i] = (fo[i] + bo[i]) * m + hidden[i] * (1.f - m);
}

__global__ void cvt_kernel(const float* __restrict__ src, u16* __restrict__ dst, int n) {
    int i = blockIdx.x * 256 + threadIdx.x;
    if (i < n) dst[i] = f2bf(src[i]);
}
__global__ void cvt_pad_kernel(const float* __restrict__ src, u16* __restrict__ dst,
                               int rows_src, int cols, int n_dst) {
    int i = blockIdx.x * 256 + threadIdx.x;
    if (i >= n_dst) return;
    int r = i / cols;
    dst[i] = (r < rows_src) ? f2bf(src[(size_t)r * cols + (i % cols)]) : (u16)0;
}
__global__ void cvt_dt_kernel(const float* __restrict__ dbc, u16* __restrict__ dst) {
    int i = blockIdx.x * 256 + threadIdx.x;   // 4096*64
    int r = i >> 6, c = i & 63;
    dst[i] = f2bf(dbc[(size_t)r * 96 + c]);
}

// ---------- launcher ----------
extern "C" void kernel_launch(void* const* d_in, const int* in_sizes, int n_in,
                              void* d_out, int out_size, void* d_ws, size_t ws_size,
                              hipStream_t stream)
{
    (void)in_sizes; (void)n_in; (void)out_size; (void)ws_size;
    const float* hidden = (const float*)d_in[0];
    const float* mask   = (const float*)d_in[1];
    const float* mpw    = (const float*)d_in[2];
    const float* mpb    = (const float*)d_in[3];

    char* ws = (char*)d_ws;
    size_t off = 0;
    auto alloc = [&](size_t bytes) -> char* {
        char* p = ws + off; off += (bytes + 255) & ~(size_t)255; return p;
    };
    u16*   xm    = (u16*)  alloc(4096ull * 1024 * 2);
    u16*   xz    = (u16*)  alloc(4096ull * 4096 * 2);
    u16*   ub    = (u16*)  alloc(4096ull * 2048 * 2);
    float* dbc   = (float*)alloc(4096ull * 96 * 4);
    u16*   dtb   = (u16*)  alloc(4096ull * 64 * 2);
    u16*   delta = (u16*)  alloc(4096ull * 2048 * 2);   // bf16 now
    u16*   yb    = (u16*)  alloc(4096ull * 2048 * 2);
    float* fout  = (float*)alloc(4096ull * 1024 * 4);
    float* bout  = (float*)alloc(4096ull * 1024 * 4);
    float* Pbuf  = (float*)alloc(2ull * NCH * 2048 * 16 * 4);   // 8 MB
    float* Sbuf  = (float*)alloc(2ull * NCH * 2048 * 16 * 4);   // 8 MB
    u16* w_in[2]  = { (u16*)alloc(4096ull*1024*2), (u16*)alloc(4096ull*1024*2) };
    u16* w_xp[2]  = { (u16*)alloc(128ull*2048*2),  (u16*)alloc(128ull*2048*2)  };
    u16* w_dt[2]  = { (u16*)alloc(2048ull*64*2),   (u16*)alloc(2048ull*64*2)   };
    u16* w_out[2] = { (u16*)alloc(1024ull*2048*2), (u16*)alloc(1024ull*2048*2) };

    for (int dir = 0; dir < 2; ++dir) {
        int base = 4 + dir * 9;
        cvt_kernel<<<(4096*1024)/256, 256, 0, stream>>>((const float*)d_in[base+0], w_in[dir], 4096*1024);
        cvt_pad_kernel<<<(128*2048)/256, 256, 0, stream>>>((const float*)d_in[base+3], w_xp[dir], 96, 2048, 128*2048);
        cvt_kernel<<<(2048*64)/256, 256, 0, stream>>>((const float*)d_in[base+4], w_dt[dir], 2048*64);
        cvt_kernel<<<(1024*2048)/256, 256, 0, stream>>>((const float*)d_in[base+8], w_out[dir], 1024*2048);
    }
    blend_kernel<<<16384, 256, 0, stream>>>(hidden, mask, mpw, mpb, xm);

    for (int dir = 0; dir < 2; ++dir) {
        int base = 4 + dir * 9;
        const float* conv_w = (const float*)d_in[base+1];
        const float* conv_b = (const float*)d_in[base+2];
        const float* dt_b   = (const float*)d_in[base+5];
        const float* A_log  = (const float*)d_in[base+6];
        const float* Dp     = (const float*)d_in[base+7];
        int flip = dir;

        // in_proj: xz[4096,4096] = xm @ in_w^T  (A rows flipped for bwd)
        gemm_bt_kernel<<<dim3(32, 32), 256, 0, stream>>>(
            xm, 1024, w_in[dir], nullptr, xz, nullptr, 4096, 4096, 4096, 1024, 4096, flip, 0, ACT_NONE);
        // conv + silu -> u
        conv_silu_kernel<<<dim3(8, 256), 256, 0, stream>>>(xz, conv_w, conv_b, ub);
        // xproj: dbc[4096,96] = u @ xproj_w^T  (N padded 96->128)
        gemm_bt_kernel<<<dim3(1, 32), 256, 0, stream>>>(
            ub, 2048, w_xp[dir], dbc, nullptr, nullptr, 96, 4096, 128, 2048, 96, 0, 0, ACT_NONE);
        // dt slice -> bf16
        cvt_dt_kernel<<<(4096*64)/256, 256, 0, stream>>>(dbc, dtb);
        // dt_proj + softplus -> delta (bf16)
        gemm_bt_kernel<<<dim3(16, 32), 256, 0, stream>>>(
            dtb, 64, w_dt[dir], nullptr, delta, dt_b, 2048, 4096, 2048, 64, 2048, 0, 0, ACT_SOFTPLUS);
        // chunked scan
        scan_part1<<<dim3(128, NCH, 2), 256, 0, stream>>>(delta, ub, dbc, A_log, Pbuf, Sbuf);
        scan_part2<<<256, 256, 0, stream>>>(Pbuf, Sbuf);
        scan_part3<<<dim3(128, NCH, 2), 256, 0, stream>>>(delta, ub, dbc, xz, A_log, Dp, Sbuf, yb);
        // out_proj: dir_out = y @ out_w^T  (C rows flipped for bwd)
        gemm_bt_kernel<<<dim3(8, 32), 256, 0, stream>>>(
            yb, 2048, w_out[dir], dir ? bout : fout, nullptr, nullptr, 1024, 4096, 1024, 2048, 1024, 0, flip, ACT_NONE);
    }
    final_kernel<<<16384, 256, 0, stream>>>(hidden, mask, fout, bout, (float*)d_out);
}

// Round 7
// 813.216 us; speedup vs baseline: 1.2027x; 1.2027x over previous
//
#include <hip/hip_runtime.h>
#include <hip/hip_bf16.h>
#include <stdint.h>

// ---------- types / helpers ----------
typedef unsigned short u16;
using bf16x8 = __attribute__((ext_vector_type(8))) short;  // 8 bf16 in 4 VGPRs
using f32x4  = __attribute__((ext_vector_type(4))) float;  // MFMA accumulator
typedef unsigned short u16x4 __attribute__((ext_vector_type(4)));

#define AS1 __attribute__((address_space(1)))
#define AS3 __attribute__((address_space(3)))

__device__ __forceinline__ float bf2f(u16 x) {
    union { unsigned int u; float f; } v; v.u = ((unsigned int)x) << 16; return v.f;
}
__device__ __forceinline__ u16 f2bf(float f) {
    union { float f; unsigned int u; } v; v.f = f;
    return (u16)((v.u + 0x7fffu + ((v.u >> 16) & 1u)) >> 16);  // RNE
}

#define ACT_NONE 0
#define ACT_SOFTPLUS 1

// ---------- generic bf16 GEMM: C[M,N] = A[M,K] * B[N,K]^T ----------
// 128x128 tile, BK=64, 256 threads (4 waves 2x2), 16x16x32 bf16 MFMA.
__global__ __launch_bounds__(256) void gemm_bt_kernel(
    const u16* __restrict__ A, int lda,
    const u16* __restrict__ B,              // ldb == K
    float* __restrict__ Cf, u16* __restrict__ Cb,
    const float* __restrict__ bias,
    int ldc, int M, int N, int K, int Nreal,
    int flipA, int flipC, int act)
{
    __shared__ __align__(16) u16 As[128 * 64];
    __shared__ __align__(16) u16 Bs[128 * 64];

    const int tid  = threadIdx.x;
    const int bm   = blockIdx.y * 128;
    const int bn   = blockIdx.x * 128;
    const int lane = tid & 63;
    const int wid  = tid >> 6;
    const int wr   = (wid >> 1) * 64;
    const int wc   = (wid & 1) * 64;
    const int l15  = lane & 15;
    const int l4   = lane >> 4;

    f32x4 acc[4][4];
    const f32x4 vzero = {0.f, 0.f, 0.f, 0.f};
    #pragma unroll
    for (int i = 0; i < 4; ++i)
        #pragma unroll
        for (int j = 0; j < 4; ++j) acc[i][j] = vzero;

    const int nK = K >> 6;
    for (int k0 = 0; k0 < nK; ++k0) {
        #pragma unroll
        for (int i = 0; i < 4; ++i) {
            int off  = i * 4096 + tid * 16;     // byte offset in tile
            int row  = off >> 7;
            int colB = off & 127;
            int rowG = bm + row;
            if (flipA) { int b = rowG >> 11; int l = rowG & 2047; rowG = (b << 11) + (2047 - l); }
            const char* src = (const char*)A + ((size_t)rowG * lda + ((size_t)k0 << 6)) * 2 + colB;
            __builtin_amdgcn_global_load_lds((const AS1 unsigned int*)src,
                                             (AS3 unsigned int*)((char*)As + off), 16, 0, 0);
        }
        #pragma unroll
        for (int i = 0; i < 4; ++i) {
            int off  = i * 4096 + tid * 16;
            int row  = off >> 7;
            int colB = off & 127;
            int rowG = bn + row;
            const char* src = (const char*)B + ((size_t)rowG * K + ((size_t)k0 << 6)) * 2 + colB;
            __builtin_amdgcn_global_load_lds((const AS1 unsigned int*)src,
                                             (AS3 unsigned int*)((char*)Bs + off), 16, 0, 0);
        }
        __syncthreads();

        #pragma unroll
        for (int kk = 0; kk < 2; ++kk) {
            bf16x8 af[4], bfr[4];
            #pragma unroll
            for (int mt = 0; mt < 4; ++mt) {
                int row = wr + mt * 16 + l15;
                af[mt] = *(const bf16x8*)((const char*)As + row * 128 + kk * 64 + l4 * 16);
            }
            #pragma unroll
            for (int nt = 0; nt < 4; ++nt) {
                int row = wc + nt * 16 + l15;
                bfr[nt] = *(const bf16x8*)((const char*)Bs + row * 128 + kk * 64 + l4 * 16);
            }
            #pragma unroll
            for (int mt = 0; mt < 4; ++mt)
                #pragma unroll
                for (int nt = 0; nt < 4; ++nt)
                    acc[mt][nt] = __builtin_amdgcn_mfma_f32_16x16x32_bf16(
                        af[mt], bfr[nt], acc[mt][nt], 0, 0, 0);
        }
        __syncthreads();
    }

    #pragma unroll
    for (int mt = 0; mt < 4; ++mt) {
        #pragma unroll
        for (int nt = 0; nt < 4; ++nt) {
            int col = bn + wc + nt * 16 + l15;
            if (col >= Nreal) continue;
            #pragma unroll
            for (int r = 0; r < 4; ++r) {
                int rowG = bm + wr + mt * 16 + l4 * 4 + r;
                float v = acc[mt][nt][r];
                if (act == ACT_SOFTPLUS) {
                    v += bias[col];
                    v = fmaxf(v, 0.f) + log1pf(__expf(-fabsf(v)));
                }
                int rw = rowG;
                if (flipC) { int b = rw >> 11; int l = rw & 2047; rw = (b << 11) + (2047 - l); }
                if (Cb) Cb[(size_t)rw * ldc + col] = f2bf(v);
                else    Cf[(size_t)rw * ldc + col] = v;
            }
        }
    }
}

// ---------- causal depthwise conv (w=4) + silu, sliding-window ----------
__global__ void conv_silu_kernel(const u16* __restrict__ xz,   // [4096][4096], xi = cols 0..2047
                                 const float* __restrict__ cw, // [2048][4]
                                 const float* __restrict__ cb,
                                 u16* __restrict__ u)           // [4096][2048]
{
    int d  = blockIdx.x * 256 + threadIdx.x;   // 0..2047
    int r0 = blockIdx.y * 16;                  // 16 | 2048, blocks never straddle batches
    float w0 = cw[d*4+0], w1 = cw[d*4+1], w2 = cw[d*4+2], w3 = cw[d*4+3];
    float bias = cb[d];
    float x1, x2, x3;
    if (r0 & 2047) {
        x1 = bf2f(xz[(size_t)(r0-1) * 4096 + d]);
        x2 = bf2f(xz[(size_t)(r0-2) * 4096 + d]);
        x3 = bf2f(xz[(size_t)(r0-3) * 4096 + d]);
    } else { x1 = x2 = x3 = 0.f; }
    #pragma unroll
    for (int i = 0; i < 16; ++i) {
        int r = r0 + i;
        float x0 = bf2f(xz[(size_t)r * 4096 + d]);
        float acc = fmaf(w3, x0, fmaf(w2, x1, fmaf(w1, x2, fmaf(w0, x3, bias))));
        float sig = 1.f / (1.f + __expf(-acc));
        u[(size_t)r * 2048 + d] = f2bf(acc * sig);
        x3 = x2; x2 = x1; x1 = x0;
    }
}

// ---------- chunked selective scan, register-state layout ----------
// Thread owns one channel d, all 16 states in VGPRs. No cross-lane ops.
// part1: per-chunk (P,S) from h=0.  part2: serial chunk-prefix.
// part3: re-scan from h_in, fused gate epilogue.
// P/S layout: [b][c][d][n] -> ((b*NCH+c)<<15) + d*16 + n.

#define NCH 32   // chunks per sequence
#define CSZ 64   // steps per chunk
#define SUB 16   // staged sub-chunk
#define LW  264  // padded LDS row width (256 + 8)

__global__ __launch_bounds__(256) void scan_part1(
    const u16* __restrict__ delta, const u16* __restrict__ u,
    const float* __restrict__ dbc, const float* __restrict__ A_log,
    float* __restrict__ P, float* __restrict__ S)
{
    __shared__ __align__(16) u16   dl_s[SUB * LW];
    __shared__ __align__(16) u16   ul_s[SUB * LW];
    __shared__ __align__(16) float b_s[SUB * 16];

    const int tid = threadIdx.x;
    const int d0  = blockIdx.x * 256;
    const int c   = blockIdx.y;
    const int b   = blockIdx.z;
    const int d   = d0 + tid;
    const size_t rbase = (size_t)b * 2048 + c * CSZ;

    float a2[16], h[16], p[16];
    #pragma unroll
    for (int q = 0; q < 4; ++q) {
        float4 al = *(const float4*)&A_log[(size_t)d * 16 + q * 4];
        a2[q*4+0] = -__expf(al.x) * 1.4426950408889634f;
        a2[q*4+1] = -__expf(al.y) * 1.4426950408889634f;
        a2[q*4+2] = -__expf(al.z) * 1.4426950408889634f;
        a2[q*4+3] = -__expf(al.w) * 1.4426950408889634f;
    }
    #pragma unroll
    for (int n = 0; n < 16; ++n) { h[n] = 0.f; p[n] = 1.f; }

    const int sr  = tid >> 4;          // staging row 0..15
    const int sc16 = (tid & 15) * 16;  // staging col

    for (int sch = 0; sch < CSZ / SUB; ++sch) {
        {
            size_t row = rbase + sch * SUB + sr;
            *(bf16x8*)&dl_s[sr * LW + sc16]     = *(const bf16x8*)&delta[row * 2048 + d0 + sc16];
            *(bf16x8*)&dl_s[sr * LW + sc16 + 8] = *(const bf16x8*)&delta[row * 2048 + d0 + sc16 + 8];
            *(bf16x8*)&ul_s[sr * LW + sc16]     = *(const bf16x8*)&u[row * 2048 + d0 + sc16];
            *(bf16x8*)&ul_s[sr * LW + sc16 + 8] = *(const bf16x8*)&u[row * 2048 + d0 + sc16 + 8];
            if (tid < 64) {
                int r2 = tid >> 2, c4 = (tid & 3) * 4;
                size_t g2 = rbase + sch * SUB + r2;
                *(float4*)&b_s[r2 * 16 + c4] = *(const float4*)&dbc[g2 * 96 + 64 + c4];
            }
        }
        __syncthreads();
        for (int s = 0; s < SUB; ++s) {
            float dv  = bf2f(dl_s[s * LW + tid]);
            float uv  = bf2f(ul_s[s * LW + tid]);
            float dvu = dv * uv;
            const float4* Bp = (const float4*)&b_s[s * 16];
            #pragma unroll
            for (int q = 0; q < 4; ++q) {
                float4 Bq = Bp[q];
                #pragma unroll
                for (int j = 0; j < 4; ++j) {
                    int n = q * 4 + j;
                    float dA = exp2f(dv * a2[n]);
                    h[n] = fmaf(dA, h[n], dvu * ((&Bq.x)[j]));
                    p[n] *= dA;
                }
            }
        }
        __syncthreads();
    }

    size_t base = (((size_t)(b * NCH + c)) << 15) + (size_t)d * 16;
    #pragma unroll
    for (int q = 0; q < 4; ++q) {
        float4 pv = { p[q*4+0], p[q*4+1], p[q*4+2], p[q*4+3] };
        float4 sv = { h[q*4+0], h[q*4+1], h[q*4+2], h[q*4+3] };
        *(float4*)&P[base + q * 4] = pv;
        *(float4*)&S[base + q * 4] = sv;
    }
}

__global__ void scan_part2(const float* __restrict__ P, float* __restrict__ S)
{
    int i  = blockIdx.x * 256 + threadIdx.x;   // b*32768 + d*16+n
    int b  = i >> 15;
    int dn = i & 32767;
    size_t base = ((size_t)b * NCH) << 15;
    float h = 0.f;
    #pragma unroll 4
    for (int c = 0; c < NCH; ++c) {
        size_t idx = base + ((size_t)c << 15) + dn;
        float p = P[idx];
        float s = S[idx];
        S[idx] = h;                 // h_in for chunk c
        h = fmaf(p, h, s);
    }
}

__global__ __launch_bounds__(256) void scan_part3(
    const u16* __restrict__ delta, const u16* __restrict__ u,
    const float* __restrict__ dbc, const u16* __restrict__ xz,
    const float* __restrict__ A_log, const float* __restrict__ Dp,
    const float* __restrict__ Hin, u16* __restrict__ y)
{
    __shared__ __align__(16) u16   dl_s[SUB * LW];
    __shared__ __align__(16) u16   ul_s[SUB * LW];
    __shared__ __align__(16) u16   zl_s[SUB * LW];
    __shared__ __align__(16) float bc_s[SUB * 32];   // [s][0..15]=B, [16..31]=C

    const int tid = threadIdx.x;
    const int d0  = blockIdx.x * 256;
    const int c   = blockIdx.y;
    const int b   = blockIdx.z;
    const int d   = d0 + tid;
    const size_t rbase = (size_t)b * 2048 + c * CSZ;

    float a2[16], h[16];
    #pragma unroll
    for (int q = 0; q < 4; ++q) {
        float4 al = *(const float4*)&A_log[(size_t)d * 16 + q * 4];
        a2[q*4+0] = -__expf(al.x) * 1.4426950408889634f;
        a2[q*4+1] = -__expf(al.y) * 1.4426950408889634f;
        a2[q*4+2] = -__expf(al.z) * 1.4426950408889634f;
        a2[q*4+3] = -__expf(al.w) * 1.4426950408889634f;
    }
    {
        size_t base = (((size_t)(b * NCH + c)) << 15) + (size_t)d * 16;
        #pragma unroll
        for (int q = 0; q < 4; ++q) {
            float4 hv = *(const float4*)&Hin[base + q * 4];
            h[q*4+0] = hv.x; h[q*4+1] = hv.y; h[q*4+2] = hv.z; h[q*4+3] = hv.w;
        }
    }
    const float Dd = Dp[d];

    const int sr   = tid >> 4;
    const int sc16 = (tid & 15) * 16;

    for (int sch = 0; sch < CSZ / SUB; ++sch) {
        {
            size_t row = rbase + sch * SUB + sr;
            *(bf16x8*)&dl_s[sr * LW + sc16]     = *(const bf16x8*)&delta[row * 2048 + d0 + sc16];
            *(bf16x8*)&dl_s[sr * LW + sc16 + 8] = *(const bf16x8*)&delta[row * 2048 + d0 + sc16 + 8];
            *(bf16x8*)&ul_s[sr * LW + sc16]     = *(const bf16x8*)&u[row * 2048 + d0 + sc16];
            *(bf16x8*)&ul_s[sr * LW + sc16 + 8] = *(const bf16x8*)&u[row * 2048 + d0 + sc16 + 8];
            *(bf16x8*)&zl_s[sr * LW + sc16]     = *(const bf16x8*)&xz[row * 4096 + 2048 + d0 + sc16];
            *(bf16x8*)&zl_s[sr * LW + sc16 + 8] = *(const bf16x8*)&xz[row * 4096 + 2048 + d0 + sc16 + 8];
            if (tid < 128) {
                int r2 = tid >> 3, c4 = (tid & 7) * 4;
                size_t g2 = rbase + sch * SUB + r2;
                *(float4*)&bc_s[r2 * 32 + c4] = *(const float4*)&dbc[g2 * 96 + 64 + c4];
            }
        }
        __syncthreads();
        for (int s = 0; s < SUB; ++s) {
            float dv  = bf2f(dl_s[s * LW + tid]);
            float uv  = bf2f(ul_s[s * LW + tid]);
            float dvu = dv * uv;
            float yv  = 0.f;
            const float4* Bp = (const float4*)&bc_s[s * 32];
            const float4* Cp = (const float4*)&bc_s[s * 32 + 16];
            #pragma unroll
            for (int q = 0; q < 4; ++q) {
                float4 Bq = Bp[q];
                float4 Cq = Cp[q];
                #pragma unroll
                for (int j = 0; j < 4; ++j) {
                    int n = q * 4 + j;
                    float dA = exp2f(dv * a2[n]);
                    h[n] = fmaf(dA, h[n], dvu * ((&Bq.x)[j]));
                    yv   = fmaf(h[n], ((&Cq.x)[j]), yv);
                }
            }
            float zv  = bf2f(zl_s[s * LW + tid]);
            float sig = 1.f / (1.f + __expf(-zv));
            float out = (yv + uv * Dd) * (zv * sig);
            y[(rbase + sch * SUB + s) * 2048 + d] = f2bf(out);
        }
        __syncthreads();
    }
}

// ---------- elementwise ----------
__global__ void blend_kernel(const float* __restrict__ hidden, const float* __restrict__ mask,
                             const float* __restrict__ mw, const float* __restrict__ mb,
                             u16* __restrict__ xm)
{
    size_t i = (size_t)blockIdx.x * 256 + threadIdx.x;
    int r = (int)(i >> 10), c = (int)(i & 1023);
    float m = mask[r];
    float v = hidden[i] * m + (m * mw[c] + mb[c]) * (1.f - m);
    xm[i] = f2bf(v);
}

__global__ void final_kernel(const float* __restrict__ hidden, const float* __restrict__ mask,
                             const float* __restrict__ fo, const float* __restrict__ bo,
                             float* __restrict__ out)
{
    size_t i = (size_t)blockIdx.x * 256 + threadIdx.x;
    int r = (int)(i >> 10);
    float m = mask[r];
    out[i] = (fo[i] + bo[i]) * m + hidden[i] * (1.f - m);
}

__global__ void cvt_kernel(const float* __restrict__ src, u16* __restrict__ dst, int n) {
    int i = blockIdx.x * 256 + threadIdx.x;
    if (i < n) dst[i] = f2bf(src[i]);
}
__global__ void cvt_pad_kernel(const float* __restrict__ src, u16* __restrict__ dst,
                               int rows_src, int cols, int n_dst) {
    int i = blockIdx.x * 256 + threadIdx.x;
    if (i >= n_dst) return;
    int r = i / cols;
    dst[i] = (r < rows_src) ? f2bf(src[(size_t)r * cols + (i % cols)]) : (u16)0;
}
__global__ void cvt_dt_kernel(const float* __restrict__ dbc, u16* __restrict__ dst) {
    int i = blockIdx.x * 256 + threadIdx.x;   // 4096*64
    int r = i >> 6, c = i & 63;
    dst[i] = f2bf(dbc[(size_t)r * 96 + c]);
}

// ---------- launcher ----------
extern "C" void kernel_launch(void* const* d_in, const int* in_sizes, int n_in,
                              void* d_out, int out_size, void* d_ws, size_t ws_size,
                              hipStream_t stream)
{
    (void)in_sizes; (void)n_in; (void)out_size; (void)ws_size;
    const float* hidden = (const float*)d_in[0];
    const float* mask   = (const float*)d_in[1];
    const float* mpw    = (const float*)d_in[2];
    const float* mpb    = (const float*)d_in[3];

    char* ws = (char*)d_ws;
    size_t off = 0;
    auto alloc = [&](size_t bytes) -> char* {
        char* p = ws + off; off += (bytes + 255) & ~(size_t)255; return p;
    };
    u16*   xm    = (u16*)  alloc(4096ull * 1024 * 2);
    u16*   xz    = (u16*)  alloc(4096ull * 4096 * 2);
    u16*   ub    = (u16*)  alloc(4096ull * 2048 * 2);
    float* dbc   = (float*)alloc(4096ull * 96 * 4);
    u16*   dtb   = (u16*)  alloc(4096ull * 64 * 2);
    u16*   delta = (u16*)  alloc(4096ull * 2048 * 2);   // bf16
    u16*   yb    = (u16*)  alloc(4096ull * 2048 * 2);
    float* fout  = (float*)alloc(4096ull * 1024 * 4);
    float* bout  = (float*)alloc(4096ull * 1024 * 4);
    float* Pbuf  = (float*)alloc(2ull * NCH * 2048 * 16 * 4);   // 8 MB
    float* Sbuf  = (float*)alloc(2ull * NCH * 2048 * 16 * 4);   // 8 MB
    u16* w_in[2]  = { (u16*)alloc(4096ull*1024*2), (u16*)alloc(4096ull*1024*2) };
    u16* w_xp[2]  = { (u16*)alloc(128ull*2048*2),  (u16*)alloc(128ull*2048*2)  };
    u16* w_dt[2]  = { (u16*)alloc(2048ull*64*2),   (u16*)alloc(2048ull*64*2)   };
    u16* w_out[2] = { (u16*)alloc(1024ull*2048*2), (u16*)alloc(1024ull*2048*2) };

    for (int dir = 0; dir < 2; ++dir) {
        int base = 4 + dir * 9;
        cvt_kernel<<<(4096*1024)/256, 256, 0, stream>>>((const float*)d_in[base+0], w_in[dir], 4096*1024);
        cvt_pad_kernel<<<(128*2048)/256, 256, 0, stream>>>((const float*)d_in[base+3], w_xp[dir], 96, 2048, 128*2048);
        cvt_kernel<<<(2048*64)/256, 256, 0, stream>>>((const float*)d_in[base+4], w_dt[dir], 2048*64);
        cvt_kernel<<<(1024*2048)/256, 256, 0, stream>>>((const float*)d_in[base+8], w_out[dir], 1024*2048);
    }
    blend_kernel<<<16384, 256, 0, stream>>>(hidden, mask, mpw, mpb, xm);

    for (int dir = 0; dir < 2; ++dir) {
        int base = 4 + dir * 9;
        const float* conv_w = (const float*)d_in[base+1];
        const float* conv_b = (const float*)d_in[base+2];
        const float* dt_b   = (const float*)d_in[base+5];
        const float* A_log  = (const float*)d_in[base+6];
        const float* Dp     = (const float*)d_in[base+7];
        int flip = dir;

        gemm_bt_kernel<<<dim3(32, 32), 256, 0, stream>>>(
            xm, 1024, w_in[dir], nullptr, xz, nullptr, 4096, 4096, 4096, 1024, 4096, flip, 0, ACT_NONE);
        conv_silu_kernel<<<dim3(8, 256), 256, 0, stream>>>(xz, conv_w, conv_b, ub);
        gemm_bt_kernel<<<dim3(1, 32), 256, 0, stream>>>(
            ub, 2048, w_xp[dir], dbc, nullptr, nullptr, 96, 4096, 128, 2048, 96, 0, 0, ACT_NONE);
        cvt_dt_kernel<<<(4096*64)/256, 256, 0, stream>>>(dbc, dtb);
        gemm_bt_kernel<<<dim3(16, 32), 256, 0, stream>>>(
            dtb, 64, w_dt[dir], nullptr, delta, dt_b, 2048, 4096, 2048, 64, 2048, 0, 0, ACT_SOFTPLUS);
        scan_part1<<<dim3(8, NCH, 2), 256, 0, stream>>>(delta, ub, dbc, A_log, Pbuf, Sbuf);
        scan_part2<<<256, 256, 0, stream>>>(Pbuf, Sbuf);
        scan_part3<<<dim3(8, NCH, 2), 256, 0, stream>>>(delta, ub, dbc, xz, A_log, Dp, Sbuf, yb);
        gemm_bt_kernel<<<dim3(8, 32), 256, 0, stream>>>(
            yb, 2048, w_out[dir], dir ? bout : fout, nullptr, nullptr, 1024, 4096, 1024, 2048, 1024, 0, flip, ACT_NONE);
    }
    final_kernel<<<16384, 256, 0, stream>>>(hidden, mask, fout, bout, (float*)d_out);
}